// Round 9
// baseline (466.017 us; speedup 1.0000x reference)
//
#include <hip/hip_runtime.h>

typedef _Float16 f16_t;
typedef f16_t f16x8 __attribute__((ext_vector_type(8)));
typedef float f32x4 __attribute__((ext_vector_type(4)));

#define DEVI __device__ __forceinline__

constexpr int NB    = 64;
constexpr int NTOK  = 197;
constexpr int NH    = 12;
constexpr int DIM   = 768;
constexpr int M_TOK = NB * NTOK;   // 12608
constexpr int NPAD  = 224;         // 14*16 padded token count
constexpr float SCALE = 0.125f;    // 64^-0.5

// attn LDS geometry
constexpr int KP_SZ  = 2 * NPAD * 32;
constexpr int VTS_SZ = 7 * 64 * 32;
constexpr int P_LD   = 228;
constexpr int PW_SZ  = 16 * P_LD;
constexpr int ATTN_LDS = (KP_SZ + VTS_SZ + 8 * PW_SZ) * 2;  // 115712 B

DEVI ushort f2h_bits(float f) { _Float16 h = (_Float16)f; return __builtin_bit_cast(ushort, h); }

DEVI void gload16(const void* g, void* l) {
    __builtin_amdgcn_global_load_lds((const __attribute__((address_space(1))) void*)g,
                                     (__attribute__((address_space(3))) void*)l, 16, 0, 0);
}

// bijective XCD swizzle (m204)
DEVI int xcd_swz(int orig, int nwg) {
    const int q = nwg >> 3, r = nwg & 7;
    const int xcd = orig & 7, idx = orig >> 3;
    return (xcd < r ? xcd * (q + 1) : r * (q + 1) + (xcd - r) * q) + idx;
}

// ---------------- fused pre-pass: fp32->fp16 converts (x|Wqkv|Wproj) + bias gather ----------------
__global__ __launch_bounds__(256) void k_pre(const float* __restrict__ s0, ushort* __restrict__ d0, int n0,
                                             const float* __restrict__ s1, ushort* __restrict__ d1, int n1,
                                             const float* __restrict__ s2, ushort* __restrict__ d2, int n2,
                                             int ncvtblk,
                                             const float* __restrict__ rel_table,
                                             const int* __restrict__ rel_index,
                                             ushort* __restrict__ biash) {
    if ((int)blockIdx.x < ncvtblk) {
        int i = blockIdx.x * 256 + threadIdx.x;
        const float* s; ushort* d;
        if (i < n0)           { s = s0; d = d0; }
        else if (i < n0 + n1) { i -= n0; s = s1; d = d1; }
        else                  { i -= n0 + n1; if (i >= n2) return; s = s2; d = d2; }
        float4 v = reinterpret_cast<const float4*>(s)[i];
        ushort4 o;
        o.x = f2h_bits(v.x); o.y = f2h_bits(v.y); o.z = f2h_bits(v.z); o.w = f2h_bits(v.w);
        reinterpret_cast<ushort4*>(d)[i] = o;
    } else {
        int idx = (blockIdx.x - ncvtblk) * 256 + threadIdx.x;
        if (idx >= NH * NPAD * 256) return;
        const int j  = idx & 15;
        const int fr = (idx >> 4) & 15;
        const int i  = (idx >> 8) % NPAD;
        const int h  = (idx >> 8) / NPAD;
        const int col = j * 16 + fr;
        float v = -30000.f;
        if (i < NTOK && col < NTOK && j < 14) v = rel_table[rel_index[i * NTOK + col] * NH + h];
        biash[idx] = f2h_bits(v);
    }
}

// ===== QKV GEMM: 256x256, BK=32, 64KB LDS (2 blocks/CU), 2-phase/K-tile, full-tile vmcnt cover =====
// LDS: A[2 buf][256r x 32c] | B[2 buf][256r x 32c]  = 65536 B -> 2 blocks/CU, all 450 blocks
// co-resident (one dispatch round; cross-block overlap hides gate/barrier stalls, m97/m114 mechanism).
// Per K-tile t: STAGE(t+1) issued at TOP of E-phase; E computes ni{0,1} (16 MFMA), O computes ni{2,3};
// single vmcnt(0)+barrier at end of O -> staged loads get a full K-tile (~1200+cyc) of cover.
// Swizzle (r5, measured 0-conflict): phys granule g holds logical col-group (g&3)^((row>>1)&3);
// applied as inverse-permuted GLOBAL source + XOR'd ds_read col.
__global__ __launch_bounds__(512, 4) void k_qkv8(const ushort* __restrict__ A, const ushort* __restrict__ BT,
                                                 const float* __restrict__ b_q, const float* __restrict__ b_v,
                                                 ushort* __restrict__ outp) {
    constexpr int M = M_TOK, N = 2304, K = 768, nt = K / 32;  // 24 K-tiles
    constexpr int NWG = (N / 256) * 50;                       // 450
    extern __shared__ ushort lds[];                           // 32768 ushorts = 64 KiB
    ushort* ldsA = lds;
    ushort* ldsB = lds + 16384;
    const int tid = threadIdx.x, wid = tid >> 6, lane = tid & 63;
    const int wm = wid >> 2, wn = wid & 3;
    const int fr = lane & 15, fg = lane >> 4;
    const int bid = xcd_swz(blockIdx.y * (N / 256) + blockIdx.x, NWG);
    const int m0 = (bid / (N / 256)) * 256, n0 = (bid % (N / 256)) * 256;

    // staging sources (swizzle-inverse): thread handles granules tid (rows 0-127) and tid+512 (rows 128-255)
    const int srow = tid >> 2;
    const int sc = ((tid & 3) ^ ((tid >> 3) & 3)) * 8;
    int ra0 = m0 + srow;       ra0 = ra0 < M ? ra0 : M - 1;
    int ra1 = m0 + srow + 128; ra1 = ra1 < M ? ra1 : M - 1;
    const ushort* pA0 = A + (size_t)ra0 * K + sc;
    const ushort* pA1 = A + (size_t)ra1 * K + sc;
    const ushort* pB0 = BT + (size_t)(n0 + srow) * K + sc;
    const ushort* pB1 = BT + (size_t)(n0 + srow + 128) * K + sc;
    const int dstt = tid * 8;

    int aoff[8], boff[4];
#pragma unroll
    for (int mi = 0; mi < 8; ++mi) {
        const int r = wm * 128 + mi * 16 + fr;
        aoff[mi] = r * 32 + ((fg ^ ((r >> 1) & 3)) * 8);
    }
#pragma unroll
    for (int j = 0; j < 4; ++j) {
        const int c = wn * 64 + j * 16 + fr;
        boff[j] = c * 32 + ((fg ^ ((c >> 1) & 3)) * 8);
    }

    f32x4 acc[8][4] = {};
    f16x8 av[8];

    auto STAGE = [&](int t) {               // 4 gload16: A + B unit of tile t -> buf t&1
        const size_t so = (size_t)t * 32;
        const int db = (t & 1) * 8192 + dstt;
        gload16(pA0 + so, ldsA + db);
        gload16(pA1 + so, ldsA + db + 4096);
        gload16(pB0 + so, ldsB + db);
        gload16(pB1 + so, ldsB + db + 4096);
    };

    // prologue: stage tile 0, drain, barrier
    STAGE(0);
    asm volatile("s_waitcnt vmcnt(0)" ::: "memory");
    __builtin_amdgcn_sched_barrier(0);
    __builtin_amdgcn_s_barrier();

    for (int t = 0; t < nt; ++t) {
        const int buf = t & 1;
        if (t + 1 < nt) STAGE(t + 1);       // issue next-tile loads FIRST (max latency cover)
        // E phase: A frags (held through O) + B ni{0,1}
#pragma unroll
        for (int mi = 0; mi < 8; ++mi)
            av[mi] = *(const f16x8*)(ldsA + buf * 8192 + aoff[mi]);
        f16x8 bv0 = *(const f16x8*)(ldsB + buf * 8192 + boff[0]);
        f16x8 bv1 = *(const f16x8*)(ldsB + buf * 8192 + boff[1]);
        __builtin_amdgcn_s_barrier();
        __builtin_amdgcn_s_setprio(1);
#pragma unroll
        for (int mi = 0; mi < 8; ++mi) {
            acc[mi][0] = __builtin_amdgcn_mfma_f32_16x16x32_f16(av[mi], bv0, acc[mi][0], 0, 0, 0);
            acc[mi][1] = __builtin_amdgcn_mfma_f32_16x16x32_f16(av[mi], bv1, acc[mi][1], 0, 0, 0);
        }
        __builtin_amdgcn_s_setprio(0);
        __builtin_amdgcn_s_barrier();
        // O phase: B ni{2,3}
        f16x8 bv2 = *(const f16x8*)(ldsB + buf * 8192 + boff[2]);
        f16x8 bv3 = *(const f16x8*)(ldsB + buf * 8192 + boff[3]);
        __builtin_amdgcn_s_setprio(1);
#pragma unroll
        for (int mi = 0; mi < 8; ++mi) {
            acc[mi][2] = __builtin_amdgcn_mfma_f32_16x16x32_f16(av[mi], bv2, acc[mi][2], 0, 0, 0);
            acc[mi][3] = __builtin_amdgcn_mfma_f32_16x16x32_f16(av[mi], bv3, acc[mi][3], 0, 0, 0);
        }
        __builtin_amdgcn_s_setprio(0);
        asm volatile("s_waitcnt lgkmcnt(0)" ::: "memory");   // all reads of buf done (WAR vs stage t+2)
        __builtin_amdgcn_sched_barrier(0);
        asm volatile("s_waitcnt vmcnt(0)" ::: "memory");     // tile t+1 staged (RAW for next E)
        __builtin_amdgcn_sched_barrier(0);
        __builtin_amdgcn_s_barrier();
    }

    // epilogue: two 64-row half-passes through 64KB wave-private scratch -> coalesced 16B stores
    ushort* ws = lds + wid * 4096;          // [64][64] per wave
#pragma unroll
    for (int half = 0; half < 2; ++half) {
#pragma unroll
        for (int ni = 0; ni < 4; ++ni) {
            const int col = n0 + wn * 64 + ni * 16 + fr;
            float addv, mul;
            if (col < 768)       { addv = b_q[col]; mul = SCALE; }
            else if (col < 1536) { addv = 0.f; mul = 1.f; }
            else                 { addv = b_v[col - 1536]; mul = 1.f; }
#pragma unroll
            for (int mi2 = 0; mi2 < 4; ++mi2) {
                const int mi = half * 4 + mi2;
#pragma unroll
                for (int r = 0; r < 4; ++r)
                    ws[(mi2 * 16 + fg * 4 + r) * 64 + ni * 16 + fr] = f2h_bits((acc[mi][ni][r] + addv) * mul);
            }
        }
        __syncthreads();
#pragma unroll
        for (int it = 0; it < 8; ++it) {
            const int g = it * 64 + lane;
            const int r = g >> 3, seg = g & 7;
            const int row = m0 + wm * 128 + half * 64 + r;
            uint4 v = *(const uint4*)(ws + r * 64 + seg * 8);
            if (row < M) *(uint4*)(outp + (size_t)row * N + n0 + wn * 64 + seg * 8) = v;
        }
        __syncthreads();
    }
}

// ---------------- 128x128 BT GEMM, BK=32, dbuf, XOR-swizzled + XCD swizzle (proj) ----------------
template<int EPI>
__global__ __launch_bounds__(256) void k_gemm(const ushort* __restrict__ A, const ushort* __restrict__ BT,
                                              int M, int N, int K, int nwg,
                                              const float* __restrict__ b_q, const float* __restrict__ b_v,
                                              const float* __restrict__ b_p,
                                              ushort* __restrict__ out_h, float* __restrict__ out_f) {
    __shared__ __align__(16) ushort lds[2][8192];
    const int tid = threadIdx.x, wid = tid >> 6, lane = tid & 63;
    const int wm = wid >> 1, wn = wid & 1;
    const int fr = lane & 15, fg = lane >> 4;
    const int nbx = N / 128;
    const int bid = xcd_swz(blockIdx.y * nbx + blockIdx.x, nwg);
    const int m0 = (bid / nbx) * 128, n0 = (bid % nbx) * 128;

    int rA[2], rB[2], cs[2], dst[2];
#pragma unroll
    for (int i = 0; i < 2; ++i) {
        const int g = (wid * 2 + i) * 64 + lane;
        const int row = g >> 2, sp = g & 3;
        cs[i]  = (sp ^ ((row >> 1) & 3)) * 8;
        dst[i] = (wid * 2 + i) * 512;
        const int ra = m0 + row;
        rA[i] = ra < M ? ra : M - 1;
        rB[i] = n0 + row;
    }

    f32x4 acc[4][4] = {};
    const int nt = K / 32;

    auto stage = [&](int t, int buf) {
#pragma unroll
        for (int i = 0; i < 2; ++i)
            gload16(A + (size_t)rA[i] * K + t * 32 + cs[i], &lds[buf][dst[i]]);
#pragma unroll
        for (int i = 0; i < 2; ++i)
            gload16(BT + (size_t)rB[i] * K + t * 32 + cs[i], &lds[buf][4096 + dst[i]]);
    };

    stage(0, 0);
    __syncthreads();
    for (int t = 0; t < nt; ++t) {
        const int cur = t & 1;
        if (t + 1 < nt) stage(t + 1, cur ^ 1);
        const ushort* As = lds[cur];
        const ushort* Bs = lds[cur] + 4096;
        f16x8 af[4], bf[4];
#pragma unroll
        for (int i = 0; i < 4; ++i) {
            const int r = wm * 64 + i * 16 + fr;
            af[i] = *(const f16x8*)(As + r * 32 + ((fg ^ ((r >> 1) & 3)) * 8));
        }
#pragma unroll
        for (int i = 0; i < 4; ++i) {
            const int c = wn * 64 + i * 16 + fr;
            bf[i] = *(const f16x8*)(Bs + c * 32 + ((fg ^ ((c >> 1) & 3)) * 8));
        }
#pragma unroll
        for (int mi = 0; mi < 4; ++mi)
#pragma unroll
            for (int ni = 0; ni < 4; ++ni)
                acc[mi][ni] = __builtin_amdgcn_mfma_f32_16x16x32_f16(af[mi], bf[ni], acc[mi][ni], 0, 0, 0);
        __syncthreads();
    }

#pragma unroll
    for (int ni = 0; ni < 4; ++ni) {
        const int col = n0 + wn * 64 + ni * 16 + fr;
        float addv = 0.f, mul = 1.f;
        if (EPI == 0) {
            if (col < 768)       { addv = b_q[col]; mul = SCALE; }
            else if (col < 1536) { addv = 0.f; }
            else                 { addv = b_v[col - 1536]; }
        } else {
            addv = b_p[col];
        }
#pragma unroll
        for (int mi = 0; mi < 4; ++mi) {
#pragma unroll
            for (int r = 0; r < 4; ++r) {
                const int row = m0 + wm * 64 + mi * 16 + fg * 4 + r;
                if (row < M) {
                    float v = (acc[mi][ni][r] + addv) * mul;
                    if (EPI == 0) out_h[(size_t)row * N + col] = f2h_bits(v);
                    else          out_f[(size_t)row * N + col] = v;
                }
            }
        }
    }
}

// ================ fused attention v3: block=(b,h), 8 waves, conflict-free LDS ================
__global__ __launch_bounds__(512) void k_attn(const ushort* __restrict__ qkv,
                                              const ushort* __restrict__ biash, ushort* __restrict__ out) {
    extern __shared__ ushort sm[];
    ushort* kp  = sm;
    ushort* vts = sm + KP_SZ;
    ushort* ps  = sm + KP_SZ + VTS_SZ;
    const int tid = threadIdx.x, wid = tid >> 6, lane = tid & 63;
    const int fr = lane & 15, fg = lane >> 4;
    const int bh = blockIdx.x;
    const int b = bh / NH, h = bh % NH;
    const size_t qb = (size_t)(b * NTOK) * 2304;
    const int swz8 = (fg ^ ((fr >> 1) & 3)) * 8;

    ushort* vtile = ps;
    for (int t = tid; t < NPAD * 8; t += 512) {
        const int row = t >> 3, seg = t & 7;
        uint4 kv = make_uint4(0u, 0u, 0u, 0u), vv = make_uint4(0u, 0u, 0u, 0u);
        if (row < NTOK) {
            const ushort* src = qkv + qb + (size_t)row * 2304 + 768 + h * 64;
            kv = *reinterpret_cast<const uint4*>(src + seg * 8);
            vv = *reinterpret_cast<const uint4*>(src + 768 + seg * 8);
        }
        const int pcg = (seg & 3) ^ ((row >> 1) & 3);
        *reinterpret_cast<uint4*>(kp + (seg >> 2) * (NPAD * 32) + row * 32 + pcg * 8) = kv;
        *reinterpret_cast<uint4*>(vtile + row * 72 + seg * 8) = vv;
    }
    __syncthreads();
    for (int o = tid; o < 7 * 64 * 4; o += 512) {
        const int kc = o >> 8, rem = o & 255, d = rem >> 2, pcg = rem & 3;
        const int k0 = kc * 32 + (pcg ^ ((d >> 1) & 3)) * 8;
        ushort w[8];
#pragma unroll
        for (int e = 0; e < 8; ++e) w[e] = vtile[(k0 + e) * 72 + d];
        uint4 val;
        val.x = (uint)w[0] | ((uint)w[1] << 16);
        val.y = (uint)w[2] | ((uint)w[3] << 16);
        val.z = (uint)w[4] | ((uint)w[5] << 16);
        val.w = (uint)w[6] | ((uint)w[7] << 16);
        *reinterpret_cast<uint4*>(vts + kc * 2048 + d * 32 + pcg * 8) = val;
    }
    __syncthreads();

    ushort* pw = ps + wid * PW_SZ;

    for (int s = wid; s < 13; s += 8) {
        const int q0 = s * 16;
        f16x8 qf[2];
        {
            int row = q0 + fr;
            row = row < NTOK ? row : NTOK - 1;
            const ushort* qp = qkv + qb + (size_t)row * 2304 + h * 64 + fg * 8;
            qf[0] = *reinterpret_cast<const f16x8*>(qp);
            qf[1] = *reinterpret_cast<const f16x8*>(qp + 32);
        }
        f32x4 sacc[14] = {};
#pragma unroll
        for (int j = 0; j < 14; ++j) {
#pragma unroll
            for (int kh = 0; kh < 2; ++kh) {
                f16x8 kf = *reinterpret_cast<const f16x8*>(kp + kh * (NPAD * 32) + (j * 16 + fr) * 32 + swz8);
                sacc[j] = __builtin_amdgcn_mfma_f32_16x16x32_f16(qf[kh], kf, sacc[j], 0, 0, 0);
            }
        }
        float rs4[4];
#pragma unroll
        for (int r = 0; r < 4; ++r) {
            const int qrow_l = fg * 4 + r;
            int qrow = q0 + qrow_l;
            qrow = qrow < NTOK ? qrow : NTOK - 1;
            const ushort* bp16 = biash + (((size_t)(h * NPAD + qrow) * 16 + fr) << 4);
            f16x8 bv0 = *reinterpret_cast<const f16x8*>(bp16);
            f16x8 bv1 = *reinterpret_cast<const f16x8*>(bp16 + 8);
            float mx = -1e30f;
#pragma unroll
            for (int j = 0; j < 14; ++j) {
                const float bj = (float)(j < 8 ? bv0[j] : bv1[j - 8]);
                float v = sacc[j][r] + bj;
                sacc[j][r] = v;
                mx = fmaxf(mx, v);
            }
            mx = fmaxf(mx, __shfl_xor(mx, 1));
            mx = fmaxf(mx, __shfl_xor(mx, 2));
            mx = fmaxf(mx, __shfl_xor(mx, 4));
            mx = fmaxf(mx, __shfl_xor(mx, 8));
            float sum = 0.f;
            ushort* prow = pw + qrow_l * P_LD;
#pragma unroll
            for (int j = 0; j < 14; ++j) {
                float p = __expf(sacc[j][r] - mx);
                sum += p;
                prow[j * 16 + fr] = f2h_bits(p);
            }
            sum += __shfl_xor(sum, 1);
            sum += __shfl_xor(sum, 2);
            sum += __shfl_xor(sum, 4);
            sum += __shfl_xor(sum, 8);
            rs4[r] = sum;
        }
        f32x4 o[4] = {};
#pragma unroll
        for (int kc = 0; kc < 7; ++kc) {
            f16x8 af = *reinterpret_cast<const f16x8*>(pw + fr * P_LD + kc * 32 + fg * 8);
#pragma unroll
            for (int dt = 0; dt < 4; ++dt) {
                f16x8 bv = *reinterpret_cast<const f16x8*>(vts + kc * 2048 + (dt * 16 + fr) * 32 + swz8);
                o[dt] = __builtin_amdgcn_mfma_f32_16x16x32_f16(af, bv, o[dt], 0, 0, 0);
            }
        }
#pragma unroll
        for (int dt = 0; dt < 4; ++dt) {
#pragma unroll
            for (int r = 0; r < 4; ++r) {
                const int qrow = q0 + fg * 4 + r;
                if (qrow < NTOK) {
                    const float val = o[dt][r] / rs4[r];
                    out[(size_t)(b * NTOK + qrow) * DIM + h * 64 + dt * 16 + fr] = f2h_bits(val);
                }
            }
        }
    }
}

extern "C" void kernel_launch(void* const* d_in, const int* in_sizes, int n_in,
                              void* d_out, int out_size, void* d_ws, size_t ws_size,
                              hipStream_t stream) {
    const float* x         = (const float*)d_in[0];
    const float* Wqkv      = (const float*)d_in[1];
    const float* q_bias    = (const float*)d_in[2];
    const float* v_bias    = (const float*)d_in[3];
    const float* rel_table = (const float*)d_in[4];
    const float* Wproj     = (const float*)d_in[5];
    const float* bproj     = (const float*)d_in[6];
    const int*   rel_index = (const int*)d_in[7];
    float* out = (float*)d_out;

    char* p = (char*)d_ws;
    auto alloc = [&](size_t bytes) { char* r = p; p += (bytes + 255) & ~(size_t)255; return r; };
    ushort* xb     = (ushort*)alloc((size_t)M_TOK * DIM * 2);
    ushort* wqkvb  = (ushort*)alloc((size_t)2304 * 768 * 2);
    ushort* wprojb = (ushort*)alloc((size_t)768 * 768 * 2);
    ushort* qkvb   = (ushort*)alloc((size_t)M_TOK * 2304 * 2);
    ushort* biasb  = (ushort*)alloc((size_t)NH * NPAD * 256 * 2);
    ushort* aob    = (ushort*)alloc((size_t)M_TOK * DIM * 2);

    (void)hipFuncSetAttribute((const void*)k_qkv8, hipFuncAttributeMaxDynamicSharedMemorySize, 65536);
    (void)hipFuncSetAttribute((const void*)k_attn, hipFuncAttributeMaxDynamicSharedMemorySize, ATTN_LDS);

    const int n0 = M_TOK * DIM / 4, n1 = 2304 * 768 / 4, n2 = 768 * 768 / 4;
    const int ncvtblk = (n0 + n1 + n2 + 255) / 256;
    const int nbiasblk = (NH * NPAD * 256 + 255) / 256;
    k_pre<<<ncvtblk + nbiasblk, 256, 0, stream>>>(x, xb, n0, Wqkv, wqkvb, n1, Wproj, wprojb, n2,
                                                  ncvtblk, rel_table, rel_index, biasb);

    k_qkv8<<<dim3(2304 / 256, (M_TOK + 255) / 256), 512, 65536, stream>>>(
        xb, wqkvb, q_bias, v_bias, qkvb);
    k_attn<<<dim3(NB * NH), 512, ATTN_LDS, stream>>>(qkvb, biasb, aob);
    k_gemm<1><<<dim3(768 / 128, (M_TOK + 127) / 128), 256, 0, stream>>>(
        aob, wprojb, M_TOK, 768, 768, (768 / 128) * ((M_TOK + 127) / 128),
        nullptr, nullptr, bproj, nullptr, out);
}

// Round 10
// 147.057 us; speedup vs baseline: 3.1690x; 3.1690x over previous
//
#include <hip/hip_runtime.h>

typedef _Float16 f16_t;
typedef f16_t f16x8 __attribute__((ext_vector_type(8)));
typedef float f32x4 __attribute__((ext_vector_type(4)));

#define DEVI __device__ __forceinline__

constexpr int NB    = 64;
constexpr int NTOK  = 197;
constexpr int NH    = 12;
constexpr int DIM   = 768;
constexpr int M_TOK = NB * NTOK;   // 12608
constexpr int NPAD  = 224;         // 14*16 padded token count
constexpr float SCALE = 0.125f;    // 64^-0.5

// attn LDS geometry
constexpr int KP_SZ  = 2 * NPAD * 32;
constexpr int VTS_SZ = 7 * 64 * 32;
constexpr int P_LD   = 228;
constexpr int PW_SZ  = 16 * P_LD;
constexpr int ATTN_LDS = (KP_SZ + VTS_SZ + 8 * PW_SZ) * 2;  // 115712 B

DEVI ushort f2h_bits(float f) { _Float16 h = (_Float16)f; return __builtin_bit_cast(ushort, h); }

DEVI void gload16(const void* g, void* l) {
    __builtin_amdgcn_global_load_lds((const __attribute__((address_space(1))) void*)g,
                                     (__attribute__((address_space(3))) void*)l, 16, 0, 0);
}

// bijective XCD swizzle (m204)
DEVI int xcd_swz(int orig, int nwg) {
    const int q = nwg >> 3, r = nwg & 7;
    const int xcd = orig & 7, idx = orig >> 3;
    return (xcd < r ? xcd * (q + 1) : r * (q + 1) + (xcd - r) * q) + idx;
}

// ---------------- fused pre-pass: fp32->fp16 converts (x|Wqkv|Wproj) + bias gather ----------------
__global__ __launch_bounds__(256) void k_pre(const float* __restrict__ s0, ushort* __restrict__ d0, int n0,
                                             const float* __restrict__ s1, ushort* __restrict__ d1, int n1,
                                             const float* __restrict__ s2, ushort* __restrict__ d2, int n2,
                                             int ncvtblk,
                                             const float* __restrict__ rel_table,
                                             const int* __restrict__ rel_index,
                                             ushort* __restrict__ biash) {
    if ((int)blockIdx.x < ncvtblk) {
        int i = blockIdx.x * 256 + threadIdx.x;
        const float* s; ushort* d;
        if (i < n0)           { s = s0; d = d0; }
        else if (i < n0 + n1) { i -= n0; s = s1; d = d1; }
        else                  { i -= n0 + n1; if (i >= n2) return; s = s2; d = d2; }
        float4 v = reinterpret_cast<const float4*>(s)[i];
        ushort4 o;
        o.x = f2h_bits(v.x); o.y = f2h_bits(v.y); o.z = f2h_bits(v.z); o.w = f2h_bits(v.w);
        reinterpret_cast<ushort4*>(d)[i] = o;
    } else {
        int idx = (blockIdx.x - ncvtblk) * 256 + threadIdx.x;
        if (idx >= NH * NPAD * 256) return;
        const int j  = idx & 15;
        const int fr = (idx >> 4) & 15;
        const int i  = (idx >> 8) % NPAD;
        const int h  = (idx >> 8) / NPAD;
        const int col = j * 16 + fr;
        float v = -30000.f;
        if (i < NTOK && col < NTOK && j < 14) v = rel_table[rel_index[i * NTOK + col] * NH + h];
        biash[idx] = f2h_bits(v);
    }
}

// ================= QKV GEMM: 256x256, BK=64, 8-phase counted-vmcnt + XCD swizzle =================
// (round-8 version: the known-good 60us config. NOTE: no launch_bounds min-waves hint — the 256^2
//  tile needs ~160 regs/wave (128 acc AGPR + frags); forcing 4 waves/EU spills acc to scratch.)
__global__ __launch_bounds__(512, 2) void k_qkv8(const ushort* __restrict__ A, const ushort* __restrict__ BT,
                                                 const float* __restrict__ b_q, const float* __restrict__ b_v,
                                                 ushort* __restrict__ outp) {
    constexpr int M = M_TOK, N = 2304, K = 768, nt = K / 64;  // nt = 12 (even)
    constexpr int NWG = (N / 256) * 50;                       // 450
    extern __shared__ ushort lds[];                           // 65536 ushorts = 128 KiB
    ushort* ldsA = lds;
    ushort* ldsB = lds + 32768;
    const int tid = threadIdx.x, wid = tid >> 6, lane = tid & 63;
    const int wm = wid >> 2, wn = wid & 3;
    const int fr = lane & 15, fg = lane >> 4;
    const int bid = xcd_swz(blockIdx.y * (N / 256) + blockIdx.x, NWG);
    const int m0 = (bid / (N / 256)) * 256, n0 = (bid % (N / 256)) * 256;

    const int srow = tid >> 2;
    const int sc = ((tid & 3) ^ ((tid >> 3) & 3)) * 8;
    int ra0 = m0 + srow;       ra0 = ra0 < M ? ra0 : M - 1;
    int ra1 = m0 + srow + 128; ra1 = ra1 < M ? ra1 : M - 1;
    const ushort* pA0 = A + (size_t)ra0 * K + sc;
    const ushort* pA1 = A + (size_t)ra1 * K + sc;
    const ushort* pB0 = BT + (size_t)(n0 + srow) * K + sc;
    const ushort* pB1 = BT + (size_t)(n0 + srow + 128) * K + sc;
    const int dstt = tid * 8;

    int aoff[8], boff[4];
#pragma unroll
    for (int mi = 0; mi < 8; ++mi) {
        const int r = wm * 128 + mi * 16 + fr;
        aoff[mi] = r * 32 + ((fg ^ ((r >> 1) & 3)) * 8);
    }
#pragma unroll
    for (int j = 0; j < 4; ++j) {
        const int c = wn * 64 + j * 16 + fr;
        boff[j] = c * 32 + ((fg ^ ((c >> 1) & 3)) * 8);
    }

    f32x4 acc[8][4] = {};
    f16x8 av[8];

    auto STAGE = [&](int T, int isA, int k) {
        const int Tw = T >= nt ? T - nt : T;
        const size_t so = (size_t)(Tw * 64 + k * 32);
        const int db = (T & 1) * 16384 + k * 8192 + dstt;
        if (isA) { gload16(pA0 + so, ldsA + db); gload16(pA1 + so, ldsA + db + 4096); }
        else     { gload16(pB0 + so, ldsB + db); gload16(pB1 + so, ldsB + db + 4096); }
    };

#define LDA8(B_, KS_) { _Pragma("unroll") for (int mi = 0; mi < 8; ++mi) \
        av[mi] = *(const f16x8*)(ldsA + (B_) * 16384 + (KS_) * 8192 + aoff[mi]); }

#define PHASE(B_, KS_, NH_, LA_, ST_T, ST_A, ST_K, GATE_) { \
        if (LA_) LDA8(B_, KS_); \
        f16x8 bv0 = *(const f16x8*)(ldsB + (B_) * 16384 + (KS_) * 8192 + boff[(NH_) * 2]); \
        f16x8 bv1 = *(const f16x8*)(ldsB + (B_) * 16384 + (KS_) * 8192 + boff[(NH_) * 2 + 1]); \
        STAGE(ST_T, ST_A, ST_K); \
        __builtin_amdgcn_s_barrier(); \
        __builtin_amdgcn_s_setprio(1); \
        _Pragma("unroll") for (int mi = 0; mi < 8; ++mi) { \
            acc[mi][(NH_) * 2]     = __builtin_amdgcn_mfma_f32_16x16x32_f16(av[mi], bv0, acc[mi][(NH_) * 2], 0, 0, 0); \
            acc[mi][(NH_) * 2 + 1] = __builtin_amdgcn_mfma_f32_16x16x32_f16(av[mi], bv1, acc[mi][(NH_) * 2 + 1], 0, 0, 0); } \
        __builtin_amdgcn_s_setprio(0); \
        asm volatile("s_waitcnt lgkmcnt(0)" ::: "memory"); \
        __builtin_amdgcn_sched_barrier(0); \
        if (GATE_) { asm volatile("s_waitcnt vmcnt(4)" ::: "memory"); __builtin_amdgcn_sched_barrier(0); } \
        __builtin_amdgcn_s_barrier(); }

    STAGE(0, 1, 0); STAGE(0, 0, 0); STAGE(0, 1, 1); STAGE(0, 0, 1);
    STAGE(1, 1, 0); STAGE(1, 0, 0);
    asm volatile("s_waitcnt vmcnt(4)" ::: "memory");
    __builtin_amdgcn_sched_barrier(0);
    __builtin_amdgcn_s_barrier();

    for (int i = 0; i < nt / 2; ++i) {
        const int t0 = 2 * i;
        PHASE(0, 0, 0, 1, t0 + 1, 1, 1, 0)
        PHASE(0, 0, 1, 0, t0 + 1, 0, 1, 0)
        PHASE(0, 1, 0, 1, t0 + 2, 1, 0, 0)
        PHASE(0, 1, 1, 0, t0 + 2, 0, 0, 1)
        PHASE(1, 0, 0, 1, t0 + 2, 1, 1, 0)
        PHASE(1, 0, 1, 0, t0 + 2, 0, 1, 0)
        PHASE(1, 1, 0, 1, t0 + 3, 1, 0, 0)
        PHASE(1, 1, 1, 0, t0 + 3, 0, 0, 1)
    }
#undef PHASE
#undef LDA8

    asm volatile("s_waitcnt vmcnt(0) lgkmcnt(0)" ::: "memory");
    __builtin_amdgcn_sched_barrier(0);
    __builtin_amdgcn_s_barrier();

    ushort* ws = lds + wid * 8192;
#pragma unroll
    for (int ni = 0; ni < 4; ++ni) {
        const int col = n0 + wn * 64 + ni * 16 + fr;
        float addv, mul;
        if (col < 768)       { addv = b_q[col]; mul = SCALE; }
        else if (col < 1536) { addv = 0.f; mul = 1.f; }
        else                 { addv = b_v[col - 1536]; mul = 1.f; }
#pragma unroll
        for (int mi = 0; mi < 8; ++mi)
#pragma unroll
            for (int r = 0; r < 4; ++r)
                ws[(mi * 16 + fg * 4 + r) * 64 + ni * 16 + fr] = f2h_bits((acc[mi][ni][r] + addv) * mul);
    }
    __syncthreads();
#pragma unroll
    for (int it = 0; it < 16; ++it) {
        const int g = it * 64 + lane;
        const int r = g >> 3, seg = g & 7;
        const int row = m0 + wm * 128 + r;
        uint4 v = *(const uint4*)(ws + r * 64 + seg * 8);
        if (row < M) *(uint4*)(outp + (size_t)row * N + n0 + wn * 64 + seg * 8) = v;
    }
}

// ---------------- 128x128 BT GEMM (proj), BK=32, dbuf, XOR-swizzled + XCD swizzle ----------------
// Epilogue now routes f32 C through the (dead) 32KB dbuf LDS for coalesced float4 stores.
// Wave-private scratch regions -> no barriers needed in the epilogue.
__global__ __launch_bounds__(256) void k_proj(const ushort* __restrict__ A, const ushort* __restrict__ BT,
                                              int M, int N, int K, int nwg,
                                              const float* __restrict__ b_p,
                                              float* __restrict__ out_f) {
    __shared__ __align__(16) ushort lds[2][8192];
    const int tid = threadIdx.x, wid = tid >> 6, lane = tid & 63;
    const int wm = wid >> 1, wn = wid & 1;
    const int fr = lane & 15, fg = lane >> 4;
    const int nbx = N / 128;
    const int bid = xcd_swz(blockIdx.y * nbx + blockIdx.x, nwg);
    const int m0 = (bid / nbx) * 128, n0 = (bid % nbx) * 128;

    int rA[2], rB[2], cs[2], dst[2];
#pragma unroll
    for (int i = 0; i < 2; ++i) {
        const int g = (wid * 2 + i) * 64 + lane;
        const int row = g >> 2, sp = g & 3;
        cs[i]  = (sp ^ ((row >> 1) & 3)) * 8;
        dst[i] = (wid * 2 + i) * 512;
        const int ra = m0 + row;
        rA[i] = ra < M ? ra : M - 1;
        rB[i] = n0 + row;
    }

    f32x4 acc[4][4] = {};
    const int nt = K / 32;

    auto stage = [&](int t, int buf) {
#pragma unroll
        for (int i = 0; i < 2; ++i)
            gload16(A + (size_t)rA[i] * K + t * 32 + cs[i], &lds[buf][dst[i]]);
#pragma unroll
        for (int i = 0; i < 2; ++i)
            gload16(BT + (size_t)rB[i] * K + t * 32 + cs[i], &lds[buf][4096 + dst[i]]);
    };

    stage(0, 0);
    __syncthreads();
    for (int t = 0; t < nt; ++t) {
        const int cur = t & 1;
        if (t + 1 < nt) stage(t + 1, cur ^ 1);
        const ushort* As = lds[cur];
        const ushort* Bs = lds[cur] + 4096;
        f16x8 af[4], bf[4];
#pragma unroll
        for (int i = 0; i < 4; ++i) {
            const int r = wm * 64 + i * 16 + fr;
            af[i] = *(const f16x8*)(As + r * 32 + ((fg ^ ((r >> 1) & 3)) * 8));
        }
#pragma unroll
        for (int i = 0; i < 4; ++i) {
            const int c = wn * 64 + i * 16 + fr;
            bf[i] = *(const f16x8*)(Bs + c * 32 + ((fg ^ ((c >> 1) & 3)) * 8));
        }
#pragma unroll
        for (int mi = 0; mi < 4; ++mi)
#pragma unroll
            for (int ni = 0; ni < 4; ++ni)
                acc[mi][ni] = __builtin_amdgcn_mfma_f32_16x16x32_f16(af[mi], bf[ni], acc[mi][ni], 0, 0, 0);
        __syncthreads();
    }

    // epilogue: wave-private f32 scratch [32][64] in the dead dbuf LDS -> coalesced float4 stores.
    // LDS write swizzle: col ^ (((lrow>>2)&3)<<4)  ((lrow>>2)&3 == fg -> fg groups hit distinct
    // 16-word groups, conflict-free). Same XOR on read keeps float4 contiguity (4 | 16).
    float* wsf = reinterpret_cast<float*>(&lds[0][0]) + wid * 2048;   // 8KB per wave
#pragma unroll
    for (int half = 0; half < 2; ++half) {
#pragma unroll
        for (int ni = 0; ni < 4; ++ni) {
            const int col = n0 + wn * 64 + ni * 16 + fr;
            const float addv = b_p[col];
#pragma unroll
            for (int mi2 = 0; mi2 < 2; ++mi2) {
                const int mi = half * 2 + mi2;
#pragma unroll
                for (int r = 0; r < 4; ++r) {
                    const int lrow = mi2 * 16 + fg * 4 + r;
                    wsf[lrow * 64 + ((ni * 16 + fr) ^ (((lrow >> 2) & 3) << 4))] = acc[mi][ni][r] + addv;
                }
            }
        }
        // wave-private RAW: compiler inserts lgkmcnt; no cross-wave hazard, no barrier.
#pragma unroll
        for (int it = 0; it < 8; ++it) {
            const int g = it * 64 + lane;
            const int lrow = g >> 4, seg = g & 15;
            const int srcc = (seg * 4) ^ (((lrow >> 2) & 3) << 4);
            float4 v = *reinterpret_cast<const float4*>(wsf + lrow * 64 + srcc);
            const int row = m0 + wm * 64 + half * 32 + lrow;
            if (row < M)
                *reinterpret_cast<float4*>(out_f + (size_t)row * N + n0 + wn * 64 + seg * 4) = v;
        }
    }
}

// ================ fused attention v3: block=(b,h), 8 waves, conflict-free LDS ================
__global__ __launch_bounds__(512) void k_attn(const ushort* __restrict__ qkv,
                                              const ushort* __restrict__ biash, ushort* __restrict__ out) {
    extern __shared__ ushort sm[];
    ushort* kp  = sm;
    ushort* vts = sm + KP_SZ;
    ushort* ps  = sm + KP_SZ + VTS_SZ;
    const int tid = threadIdx.x, wid = tid >> 6, lane = tid & 63;
    const int fr = lane & 15, fg = lane >> 4;
    const int bh = blockIdx.x;
    const int b = bh / NH, h = bh % NH;
    const size_t qb = (size_t)(b * NTOK) * 2304;
    const int swz8 = (fg ^ ((fr >> 1) & 3)) * 8;

    ushort* vtile = ps;
    for (int t = tid; t < NPAD * 8; t += 512) {
        const int row = t >> 3, seg = t & 7;
        uint4 kv = make_uint4(0u, 0u, 0u, 0u), vv = make_uint4(0u, 0u, 0u, 0u);
        if (row < NTOK) {
            const ushort* src = qkv + qb + (size_t)row * 2304 + 768 + h * 64;
            kv = *reinterpret_cast<const uint4*>(src + seg * 8);
            vv = *reinterpret_cast<const uint4*>(src + 768 + seg * 8);
        }
        const int pcg = (seg & 3) ^ ((row >> 1) & 3);
        *reinterpret_cast<uint4*>(kp + (seg >> 2) * (NPAD * 32) + row * 32 + pcg * 8) = kv;
        *reinterpret_cast<uint4*>(vtile + row * 72 + seg * 8) = vv;
    }
    __syncthreads();
    for (int o = tid; o < 7 * 64 * 4; o += 512) {
        const int kc = o >> 8, rem = o & 255, d = rem >> 2, pcg = rem & 3;
        const int k0 = kc * 32 + (pcg ^ ((d >> 1) & 3)) * 8;
        ushort w[8];
#pragma unroll
        for (int e = 0; e < 8; ++e) w[e] = vtile[(k0 + e) * 72 + d];
        uint4 val;
        val.x = (uint)w[0] | ((uint)w[1] << 16);
        val.y = (uint)w[2] | ((uint)w[3] << 16);
        val.z = (uint)w[4] | ((uint)w[5] << 16);
        val.w = (uint)w[6] | ((uint)w[7] << 16);
        *reinterpret_cast<uint4*>(vts + kc * 2048 + d * 32 + pcg * 8) = val;
    }
    __syncthreads();

    ushort* pw = ps + wid * PW_SZ;

    for (int s = wid; s < 13; s += 8) {
        const int q0 = s * 16;
        f16x8 qf[2];
        {
            int row = q0 + fr;
            row = row < NTOK ? row : NTOK - 1;
            const ushort* qp = qkv + qb + (size_t)row * 2304 + h * 64 + fg * 8;
            qf[0] = *reinterpret_cast<const f16x8*>(qp);
            qf[1] = *reinterpret_cast<const f16x8*>(qp + 32);
        }
        f32x4 sacc[14] = {};
#pragma unroll
        for (int j = 0; j < 14; ++j) {
#pragma unroll
            for (int kh = 0; kh < 2; ++kh) {
                f16x8 kf = *reinterpret_cast<const f16x8*>(kp + kh * (NPAD * 32) + (j * 16 + fr) * 32 + swz8);
                sacc[j] = __builtin_amdgcn_mfma_f32_16x16x32_f16(qf[kh], kf, sacc[j], 0, 0, 0);
            }
        }
        float rs4[4];
#pragma unroll
        for (int r = 0; r < 4; ++r) {
            const int qrow_l = fg * 4 + r;
            int qrow = q0 + qrow_l;
            qrow = qrow < NTOK ? qrow : NTOK - 1;
            const ushort* bp16 = biash + (((size_t)(h * NPAD + qrow) * 16 + fr) << 4);
            f16x8 bv0 = *reinterpret_cast<const f16x8*>(bp16);
            f16x8 bv1 = *reinterpret_cast<const f16x8*>(bp16 + 8);
            float mx = -1e30f;
#pragma unroll
            for (int j = 0; j < 14; ++j) {
                const float bj = (float)(j < 8 ? bv0[j] : bv1[j - 8]);
                float v = sacc[j][r] + bj;
                sacc[j][r] = v;
                mx = fmaxf(mx, v);
            }
            mx = fmaxf(mx, __shfl_xor(mx, 1));
            mx = fmaxf(mx, __shfl_xor(mx, 2));
            mx = fmaxf(mx, __shfl_xor(mx, 4));
            mx = fmaxf(mx, __shfl_xor(mx, 8));
            float sum = 0.f;
            ushort* prow = pw + qrow_l * P_LD;
#pragma unroll
            for (int j = 0; j < 14; ++j) {
                float p = __expf(sacc[j][r] - mx);
                sum += p;
                prow[j * 16 + fr] = f2h_bits(p);
            }
            sum += __shfl_xor(sum, 1);
            sum += __shfl_xor(sum, 2);
            sum += __shfl_xor(sum, 4);
            sum += __shfl_xor(sum, 8);
            rs4[r] = sum;
        }
        f32x4 o[4] = {};
#pragma unroll
        for (int kc = 0; kc < 7; ++kc) {
            f16x8 af = *reinterpret_cast<const f16x8*>(pw + fr * P_LD + kc * 32 + fg * 8);
#pragma unroll
            for (int dt = 0; dt < 4; ++dt) {
                f16x8 bv = *reinterpret_cast<const f16x8*>(vts + kc * 2048 + (dt * 16 + fr) * 32 + swz8);
                o[dt] = __builtin_amdgcn_mfma_f32_16x16x32_f16(af, bv, o[dt], 0, 0, 0);
            }
        }
#pragma unroll
        for (int dt = 0; dt < 4; ++dt) {
#pragma unroll
            for (int r = 0; r < 4; ++r) {
                const int qrow = q0 + fg * 4 + r;
                if (qrow < NTOK) {
                    const float val = o[dt][r] / rs4[r];
                    out[(size_t)(b * NTOK + qrow) * DIM + h * 64 + dt * 16 + fr] = f2h_bits(val);
                }
            }
        }
    }
}

extern "C" void kernel_launch(void* const* d_in, const int* in_sizes, int n_in,
                              void* d_out, int out_size, void* d_ws, size_t ws_size,
                              hipStream_t stream) {
    const float* x         = (const float*)d_in[0];
    const float* Wqkv      = (const float*)d_in[1];
    const float* q_bias    = (const float*)d_in[2];
    const float* v_bias    = (const float*)d_in[3];
    const float* rel_table = (const float*)d_in[4];
    const float* Wproj     = (const float*)d_in[5];
    const float* bproj     = (const float*)d_in[6];
    const int*   rel_index = (const int*)d_in[7];
    float* out = (float*)d_out;

    char* p = (char*)d_ws;
    auto alloc = [&](size_t bytes) { char* r = p; p += (bytes + 255) & ~(size_t)255; return r; };
    ushort* xb     = (ushort*)alloc((size_t)M_TOK * DIM * 2);
    ushort* wqkvb  = (ushort*)alloc((size_t)2304 * 768 * 2);
    ushort* wprojb = (ushort*)alloc((size_t)768 * 768 * 2);
    ushort* qkvb   = (ushort*)alloc((size_t)M_TOK * 2304 * 2);
    ushort* biasb  = (ushort*)alloc((size_t)NH * NPAD * 256 * 2);
    ushort* aob    = (ushort*)alloc((size_t)M_TOK * DIM * 2);

    (void)hipFuncSetAttribute((const void*)k_qkv8, hipFuncAttributeMaxDynamicSharedMemorySize, 131072);
    (void)hipFuncSetAttribute((const void*)k_attn, hipFuncAttributeMaxDynamicSharedMemorySize, ATTN_LDS);

    const int n0 = M_TOK * DIM / 4, n1 = 2304 * 768 / 4, n2 = 768 * 768 / 4;
    const int ncvtblk = (n0 + n1 + n2 + 255) / 256;
    const int nbiasblk = (NH * NPAD * 256 + 255) / 256;
    k_pre<<<ncvtblk + nbiasblk, 256, 0, stream>>>(x, xb, n0, Wqkv, wqkvb, n1, Wproj, wprojb, n2,
                                                  ncvtblk, rel_table, rel_index, biasb);

    k_qkv8<<<dim3(2304 / 256, (M_TOK + 255) / 256), 512, 131072, stream>>>(
        xb, wqkvb, q_bias, v_bias, qkvb);
    k_attn<<<dim3(NB * NH), 512, ATTN_LDS, stream>>>(qkvb, biasb, aob);
    k_proj<<<dim3(768 / 128, (M_TOK + 127) / 128), 256, 0, stream>>>(
        aob, wprojb, M_TOK, 768, 768, (768 / 128) * ((M_TOK + 127) / 128),
        bproj, out);
}